// Round 6
// baseline (511.615 us; speedup 1.0000x reference)
//
#include <hip/hip_runtime.h>
#include <cstdint>
#include <cstddef>

// ---- problem constants (fixed by setup_inputs) ----
// B=8, N=4000, D_IN=D_QK=512, WINDOW=128, look=1/1, SCALE=64^-0.5
#define NB    8
#define NSEQ  4000
#define NPAD  4096
#define DIM   512
#define NWIN  32          // 4096/128
#define SCALE 0.125f      // 64^-0.5
#define NEG_MAX (-3.402823466e38f)

typedef _Float16 half8 __attribute__((ext_vector_type(8)));
typedef _Float16 half4 __attribute__((ext_vector_type(4)));
typedef float    floatx4 __attribute__((ext_vector_type(4)));

typedef const __attribute__((address_space(1))) void* gas_p;
typedef __attribute__((address_space(3))) void*       las_p;

// async global->LDS, 16B per lane. LDS dest is wave-uniform base + lane*16.
__device__ __forceinline__ void gl_lds16(const void* g, void* l) {
    __builtin_amdgcn_global_load_lds((gas_p)g, (las_p)l, 16, 0, 0);
}

// ---------------------------------------------------------------------------
// K0: weights fp32 -> f16, folding SCALE into w_q. wh: [3][512][512] (n,k).
// ---------------------------------------------------------------------------
__global__ __launch_bounds__(256) void convert_w(
    const float* __restrict__ wq, const float* __restrict__ wk,
    const float* __restrict__ wv, _Float16* __restrict__ wh)
{
    int i = (blockIdx.x * 256 + threadIdx.x) * 4;
    floatx4 a = *(const floatx4*)(wq + i);
    half4 h;
    #pragma unroll
    for (int j = 0; j < 4; j++) h[j] = (_Float16)(a[j] * SCALE);
    *(half4*)(wh + i) = h;

    a = *(const floatx4*)(wk + i);
    #pragma unroll
    for (int j = 0; j < 4; j++) h[j] = (_Float16)a[j];
    *(half4*)(wh + 262144 + i) = h;

    a = *(const floatx4*)(wv + i);
    #pragma unroll
    for (int j = 0; j < 4; j++) h[j] = (_Float16)a[j];
    *(half4*)(wh + 524288 + i) = h;
}

// ---------------------------------------------------------------------------
// K1: fused projection GEMM (body identical to round 4; only block-index
// decode changed). 1-D grid 3008: g = s*8 + x, x = XCD (dispatch round-robin
// assumption), s = slot. pair = x*94 + (s>>2) -> (z, m-panel); n0 = s&3.
// The 4 col-sibling blocks of one (z,m0) share one XCD -> X panel (256 KB)
// is L2-hit for siblings 2..4 instead of 4x HBM re-fetch.
// A: reg-staged fp32->f16 (load early, cvt+ds_write late). B: f16 weights via
// global_load_lds dwordx4. LDS dbuf [k8][row][8], BK=32, 32 KB.
// z=0 -> qh [b][4096][512] (W pre-scaled by SCALE), z=1 -> kh,
// z=2 -> vT [b][512][4096]. Pad rows 4000..4095 never written.
// ---------------------------------------------------------------------------
__global__ __launch_bounds__(256) void proj_gemm(
    const float* __restrict__ xq, const float* __restrict__ xk,
    const float* __restrict__ xv, const _Float16* __restrict__ wh,
    const float* __restrict__ bq, const float* __restrict__ bk,
    const float* __restrict__ bv,
    _Float16* __restrict__ qh, _Float16* __restrict__ kh,
    _Float16* __restrict__ vT)
{
    const int g = blockIdx.x;
    const int x = g & 7, s = g >> 3;
    const int pair = x * 94 + (s >> 2);     // 0..751 (750 real)
    if (pair >= 750) return;
    const int z   = pair / 250;
    const int m0  = (pair - z * 250) * 128;
    const int n0  = (s & 3) * 128;

    const int tid = threadIdx.x;
    const int wid = tid >> 6, lane = tid & 63;
    const int l16 = lane & 15, lg = lane >> 4;
    const int wr = wid >> 1, wc = wid & 1;

    __shared__ __align__(16) _Float16 AB[2][2][4096];   // [buf][A/B][k8*1024+row*8] = 32 KB

    const float* X = (z == 0) ? xq : ((z == 1) ? xk : xv);
    const _Float16* Wz = wh + (size_t)z * DIM * DIM;

    // byte offsets within an 8 KB half-buffer: s = k8*2048 + row*16
    const int s0 = tid * 16;
    const int s1 = 4096 + tid * 16;
    const int k8_0 = s0 >> 11, row_0 = (s0 >> 4) & 127;
    const int k8_1 = s1 >> 11, row_1 = (s1 >> 4) & 127;
    const int ldsu0 = wid * 1024;          // wave-uniform chunk bases (bytes)
    const int ldsu1 = 4096 + wid * 1024;

    const float* xp0 = X + (size_t)(m0 + row_0) * DIM + k8_0 * 8;
    const float* xp1 = X + (size_t)(m0 + row_1) * DIM + k8_1 * 8;

    floatx4 acc[4][4];
    #pragma unroll
    for (int m = 0; m < 4; m++)
        #pragma unroll
        for (int n = 0; n < 4; n++) acc[m][n] = floatx4{0.f, 0.f, 0.f, 0.f};

    // ---- prologue: stage tile 0 into buf 0 ----
    {
        floatx4 a0 = *(const floatx4*)(xp0);
        floatx4 a1 = *(const floatx4*)(xp0 + 4);
        floatx4 a2 = *(const floatx4*)(xp1);
        floatx4 a3 = *(const floatx4*)(xp1 + 4);
        gl_lds16(Wz + (size_t)(n0 + row_0) * DIM + k8_0 * 8, (char*)&AB[0][1][0] + ldsu0);
        gl_lds16(Wz + (size_t)(n0 + row_1) * DIM + k8_1 * 8, (char*)&AB[0][1][0] + ldsu1);
        half8 h0, h1;
        #pragma unroll
        for (int j = 0; j < 4; j++) {
            h0[j] = (_Float16)a0[j]; h0[j + 4] = (_Float16)a1[j];
            h1[j] = (_Float16)a2[j]; h1[j + 4] = (_Float16)a3[j];
        }
        *(half8*)((char*)&AB[0][0][0] + s0) = h0;
        *(half8*)((char*)&AB[0][0][0] + s1) = h1;
    }
    __syncthreads();

    for (int ks = 0; ks < 16; ks++) {
        const int cur = ks & 1;
        floatx4 a0, a1, a2, a3;
        if (ks < 15) {
            const int k0 = (ks + 1) * 32;
            a0 = *(const floatx4*)(xp0 + k0);          // issue early (hide HBM)
            a1 = *(const floatx4*)(xp0 + k0 + 4);
            a2 = *(const floatx4*)(xp1 + k0);
            a3 = *(const floatx4*)(xp1 + k0 + 4);
            gl_lds16(Wz + (size_t)(n0 + row_0) * DIM + k0 + k8_0 * 8,
                     (char*)&AB[cur ^ 1][1][0] + ldsu0);
            gl_lds16(Wz + (size_t)(n0 + row_1) * DIM + k0 + k8_1 * 8,
                     (char*)&AB[cur ^ 1][1][0] + ldsu1);
        }
        const _Float16* Ar = &AB[cur][0][lg * 1024 + (wr * 64 + l16) * 8];
        const _Float16* Br = &AB[cur][1][lg * 1024 + (wc * 64 + l16) * 8];
        half8 af[4], bf[4];
        #pragma unroll
        for (int m = 0; m < 4; m++) af[m] = *(const half8*)(Ar + m * 128);
        #pragma unroll
        for (int n = 0; n < 4; n++) bf[n] = *(const half8*)(Br + n * 128);
        #pragma unroll
        for (int m = 0; m < 4; m++)
            #pragma unroll
            for (int n = 0; n < 4; n++)
                acc[m][n] = __builtin_amdgcn_mfma_f32_16x16x32_f16(af[m], bf[n], acc[m][n], 0, 0, 0);
        if (ks < 15) {
            half8 h0, h1;                              // cvt + write late
            #pragma unroll
            for (int j = 0; j < 4; j++) {
                h0[j] = (_Float16)a0[j]; h0[j + 4] = (_Float16)a1[j];
                h1[j] = (_Float16)a2[j]; h1[j + 4] = (_Float16)a3[j];
            }
            *(half8*)((char*)&AB[cur ^ 1][0][0] + s0) = h0;
            *(half8*)((char*)&AB[cur ^ 1][0][0] + s1) = h1;
            __syncthreads();
        }
    }

    const float* bias = (z == 0) ? bq : ((z == 1) ? bk : bv);
    const float bscale = (z == 0) ? SCALE : 1.0f;
    #pragma unroll
    for (int n = 0; n < 4; n++) {
        const int ncol = n0 + wc * 64 + n * 16 + l16;
        const float bn = bias[ncol] * bscale;
        #pragma unroll
        for (int m = 0; m < 4; m++) {
            const int r0 = m0 + wr * 64 + m * 16 + lg * 4;  // quad never splits batch
            const int bb = r0 / NSEQ;
            const int i0 = r0 - bb * NSEQ;
            if (z < 2) {
                _Float16* O = (z == 0) ? qh : kh;
                #pragma unroll
                for (int j = 0; j < 4; j++)
                    O[((size_t)(bb * NPAD + i0 + j)) * DIM + ncol] = (_Float16)(acc[m][n][j] + bn);
            } else {
                half4 pk;
                #pragma unroll
                for (int j = 0; j < 4; j++) pk[j] = (_Float16)(acc[m][n][j] + bn);
                *(half4*)(vT + ((size_t)(bb * DIM + ncol)) * NPAD + i0) = pk;
            }
        }
    }
}

// ---------------------------------------------------------------------------
// K2: FUSED attention: S = Q.K^T -> mask -> softmax -> P (LDS only) -> O = P.V.
// grid (2,32,8): x = row-half (64 q), y = window, z = batch. block 256 (4 waves;
// QK phase: wave = 16 q x 384 keys, acc[24] — identical to round 4's proven
// attn_scores). P (64x384 f16, XOR-swizzled) OVERLAYS the K double-buffer
// (both 48 KB; K dead after last MFMA, barrier in between). PV phase: per wave
// 16 q x 512 d, acc2[32]; A = 1 ds_read_b128/step from P_lds, B = V-fragments
// straight from L2/L3-resident vT (clamped rows multiply P == 0).
// ---------------------------------------------------------------------------
__global__ __launch_bounds__(256) void attn_fused(
    const _Float16* __restrict__ qh, const _Float16* __restrict__ kh,
    const _Float16* __restrict__ vT, const int* __restrict__ mask,
    float* __restrict__ out)
{
    const int h = blockIdx.x, w = blockIdx.y, b = blockIdx.z;
    const int tid = threadIdx.x;
    const int wid = tid >> 6, lane = tid & 63;
    const int l16 = lane & 15, lg = lane >> 4;

    __shared__ __align__(16) _Float16 Kl[2][12288];   // 48 KB; P overlays after QK
    char* Ps = (char*)&Kl[0][0];                      // P: byte = q*768+i*2 ^ ((q&7)<<4)

    const int kbase = w * 128 - 128;
    const _Float16* khb = kh + (size_t)b * NPAD * DIM;

    // 6 chunks of 4 KB: s = c*4096 + tid*16; k8 = s/6144; key = (s%6144)>>4
    int srcoff[6], ldsoff[6];
    #pragma unroll
    for (int c = 0; c < 6; c++) {
        int s = c * 4096 + tid * 16;
        int k8 = s / 6144;
        int key = (s - k8 * 6144) >> 4;
        int gk = kbase + key;
        int gc = gk < 0 ? 0 : (gk > NPAD - 1 ? NPAD - 1 : gk);
        srcoff[c] = gc * DIM + k8 * 8;
        ldsoff[c] = c * 4096 + wid * 1024;
    }

#define STAGE_K2(bb, k0) do {                                                   \
    _Pragma("unroll")                                                           \
    for (int c = 0; c < 6; c++)                                                 \
        gl_lds16(khb + (size_t)srcoff[c] + (k0), (char*)&Kl[bb][0] + ldsoff[c]);\
} while (0)

    const int qr0 = w * 128 + h * 64 + wid * 16;       // <= 4080
    const _Float16* qrow = qh + ((size_t)(b * NPAD + qr0 + l16)) * DIM + lg * 8;

    floatx4 acc[24];
    #pragma unroll
    for (int t = 0; t < 24; t++) acc[t] = floatx4{0.f, 0.f, 0.f, 0.f};

    half8 qcur = *(const half8*)(qrow);
    STAGE_K2(0, 0);
    __syncthreads();
    for (int ks = 0; ks < 16; ks++) {
        const int cur = ks & 1;
        half8 qnext;
        if (ks < 15) {
            STAGE_K2(cur ^ 1, (ks + 1) * 32);
            qnext = *(const half8*)(qrow + (ks + 1) * 32);
        }
        const _Float16* Kb = &Kl[cur][lg * 3072 + l16 * 8];
        #pragma unroll
        for (int t = 0; t < 24; t++) {
            half8 bf = *(const half8*)(Kb + t * 128);
            acc[t] = __builtin_amdgcn_mfma_f32_16x16x32_f16(qcur, bf, acc[t], 0, 0, 0);
        }
        if (ks < 15) { __syncthreads(); qcur = qnext; }
    }
#undef STAGE_K2

    // mask: keep iff key in [0,4000) and mask[b][g] != 0
    const int* mb = mask + b * NSEQ;
    #pragma unroll
    for (int t = 0; t < 24; t++) {
        int gk = kbase + t * 16 + l16;
        bool keep = (gk >= 0) && (gk < NSEQ) && (mb[(gk >= 0 && gk < NSEQ) ? gk : 0] != 0);
        if (!keep) acc[t] = floatx4{NEG_MAX, NEG_MAX, NEG_MAX, NEG_MAX};
    }

    __syncthreads();   // all waves past their last K-LDS reads; safe to overlay P

    #pragma unroll
    for (int j = 0; j < 4; j++) {
        float mj = NEG_MAX;
        #pragma unroll
        for (int t = 0; t < 24; t++) mj = fmaxf(mj, acc[t][j]);
        mj = fmaxf(mj, __shfl_xor(mj, 1));
        mj = fmaxf(mj, __shfl_xor(mj, 2));
        mj = fmaxf(mj, __shfl_xor(mj, 4));
        mj = fmaxf(mj, __shfl_xor(mj, 8));

        float p[24];
        float lsum = 0.f;
        #pragma unroll
        for (int t = 0; t < 24; t++) { p[t] = __expf(acc[t][j] - mj); lsum += p[t]; }
        lsum += __shfl_xor(lsum, 1);
        lsum += __shfl_xor(lsum, 2);
        lsum += __shfl_xor(lsum, 4);
        lsum += __shfl_xor(lsum, 8);
        float rinv = 1.0f / lsum;

        const int q = wid * 16 + lg * 4 + j;           // block-local q-row
        const int qswz = (q & 7) << 4;
        #pragma unroll
        for (int t = 0; t < 24; t++) {
            int byte = (q * 768 + (t * 16 + l16) * 2) ^ qswz;
            *(_Float16*)(Ps + byte) = (_Float16)(p[t] * rinv);
        }
    }

    __syncthreads();   // P complete; PV phase

    const _Float16* vb = vT + (size_t)b * DIM * NPAD;
    const int iw_base = kbase;

    floatx4 acc2[32];
    #pragma unroll
    for (int t = 0; t < 32; t++) acc2[t] = floatx4{0.f, 0.f, 0.f, 0.f};

    for (int ks = 0; ks < 12; ks++) {
        const int q = wid * 16 + l16;
        const int abyte = (q * 768 + ks * 64 + lg * 16) ^ ((q & 7) << 4);
        half8 pa = *(const half8*)(Ps + abyte);
        int ig = iw_base + ks * 32 + lg * 8;           // multiple of 8
        ig = ig < 0 ? 0 : (ig > NPAD - 8 ? NPAD - 8 : ig);   // clamped rows: P==0
        const _Float16* vrow = vb + ig;
        #pragma unroll
        for (int t = 0; t < 32; t++) {
            half8 vf = *(const half8*)(vrow + (size_t)(t * 16 + l16) * NPAD);
            acc2[t] = __builtin_amdgcn_mfma_f32_16x16x32_f16(pa, vf, acc2[t], 0, 0, 0);
        }
    }

    #pragma unroll
    for (int j = 0; j < 4; j++) {
        const int i = w * 128 + h * 64 + wid * 16 + lg * 4 + j;
        if (i < NSEQ) {
            float* orow = out + ((size_t)b * NSEQ + i) * DIM;
            #pragma unroll
            for (int t = 0; t < 32; t++) orow[t * 16 + l16] = acc2[t][j];
        }
    }
}

// ---------------------------------------------------------------------------
extern "C" void kernel_launch(void* const* d_in, const int* in_sizes, int n_in,
                              void* d_out, int out_size, void* d_ws, size_t ws_size,
                              hipStream_t stream)
{
    const float* xq = (const float*)d_in[0];
    const float* xk = (const float*)d_in[1];
    const float* xv = (const float*)d_in[2];
    const int*  msk = (const int*)d_in[3];
    const float* wq = (const float*)d_in[4];
    const float* bq = (const float*)d_in[5];
    const float* wk = (const float*)d_in[6];
    const float* bk = (const float*)d_in[7];
    const float* wv = (const float*)d_in[8];
    const float* bv = (const float*)d_in[9];

    // ws (f16 elems): qh/kh/vT 16,777,216 each | wh 786,432  (~102 MB)
    _Float16* qh = (_Float16*)d_ws;                       // [8][4096][512]
    _Float16* kh = qh + (size_t)NB * NPAD * DIM;          // [8][4096][512]
    _Float16* vT = kh + (size_t)NB * NPAD * DIM;          // [8][512][4096]
    _Float16* wh = vT + (size_t)NB * NPAD * DIM;          // [3][512][512]
    float* out = (float*)d_out;

    convert_w<<<dim3(256), dim3(256), 0, stream>>>(wq, wk, wv, wh);
    proj_gemm<<<dim3(3008), dim3(256), 0, stream>>>(
        xq, xk, xv, wh, bq, bk, bv, qh, kh, vT);
    attn_fused<<<dim3(2, NWIN, NB), dim3(256), 0, stream>>>(qh, kh, vT, msk, out);
}

// Round 7
// 393.629 us; speedup vs baseline: 1.2997x; 1.2997x over previous
//
#include <hip/hip_runtime.h>
#include <cstdint>
#include <cstddef>

// ---- problem constants (fixed by setup_inputs) ----
// B=8, N=4000, D_IN=D_QK=512, WINDOW=128, look=1/1, SCALE=64^-0.5
#define NB    8
#define NSEQ  4000
#define NPAD  4096
#define DIM   512
#define NWIN  32          // 4096/128
#define SCALE 0.125f      // 64^-0.5
#define NEG_MAX (-3.402823466e38f)

typedef _Float16 half8 __attribute__((ext_vector_type(8)));
typedef _Float16 half4 __attribute__((ext_vector_type(4)));
typedef float    floatx4 __attribute__((ext_vector_type(4)));

// ---------------------------------------------------------------------------
// K0: weights fp32 -> f16, folding SCALE into w_q. wh: [3][512][512] (n,k).
// ---------------------------------------------------------------------------
__global__ __launch_bounds__(256) void convert_w(
    const float* __restrict__ wq, const float* __restrict__ wk,
    const float* __restrict__ wv, _Float16* __restrict__ wh)
{
    int i = (blockIdx.x * 256 + threadIdx.x) * 4;
    floatx4 a = *(const floatx4*)(wq + i);
    half4 h;
    #pragma unroll
    for (int j = 0; j < 4; j++) h[j] = (_Float16)(a[j] * SCALE);
    *(half4*)(wh + i) = h;

    a = *(const floatx4*)(wk + i);
    #pragma unroll
    for (int j = 0; j < 4; j++) h[j] = (_Float16)a[j];
    *(half4*)(wh + 262144 + i) = h;

    a = *(const floatx4*)(wv + i);
    #pragma unroll
    for (int j = 0; j < 4; j++) h[j] = (_Float16)a[j];
    *(half4*)(wh + 524288 + i) = h;
}

// ---------------------------------------------------------------------------
// K1: fused projection GEMM. XCD-pairing decode (proven: FETCH 392->101 MB).
// COALESCED staging v3: lane -> (row = tid>>2 [+0/64], chunk = tid&3), so each
// wave-load covers 16 rows x 64B-within-row = 16 cache lines (was 64).
// A (fp32 X): 4 floatx4 loads early -> cvt f16 -> 2 ds_write_b128 late.
// W (f16):    2 half8 loads early -> 2 ds_write_b128 late.
// LDS layout [k8][row][8 f16] UNCHANGED (measured 0 bank conflicts); writes
// hit granule row&7 -> 8 lanes/granule = conflict-free.
// z=0 -> qh [b][4096][512] (W pre-scaled), z=1 -> kh, z=2 -> vT [b][512][4096].
// ---------------------------------------------------------------------------
__global__ __launch_bounds__(256) void proj_gemm(
    const float* __restrict__ xq, const float* __restrict__ xk,
    const float* __restrict__ xv, const _Float16* __restrict__ wh,
    const float* __restrict__ bq, const float* __restrict__ bk,
    const float* __restrict__ bv,
    _Float16* __restrict__ qh, _Float16* __restrict__ kh,
    _Float16* __restrict__ vT)
{
    const int g = blockIdx.x;
    const int x = g & 7, s = g >> 3;
    const int pair = x * 94 + (s >> 2);     // 0..751 (750 real)
    if (pair >= 750) return;
    const int z   = pair / 250;
    const int m0  = (pair - z * 250) * 128;
    const int n0  = (s & 3) * 128;

    const int tid = threadIdx.x;
    const int wid = tid >> 6, lane = tid & 63;
    const int l16 = lane & 15, lg = lane >> 4;
    const int wr = wid >> 1, wc = wid & 1;

    __shared__ __align__(16) _Float16 AB[2][2][4096];   // [buf][A/B][k8*1024+row*8] = 32 KB

    const float* X = (z == 0) ? xq : ((z == 1) ? xk : xv);
    const _Float16* Wz = wh + (size_t)z * DIM * DIM;

    // coalesced staging map
    const int srow  = tid >> 2;    // 0..63
    const int chunk = tid & 3;     // 0..3  (k8 slot)
    const float* xa0 = X + (size_t)(m0 + srow) * DIM + chunk * 8;
    const float* xa1 = X + (size_t)(m0 + 64 + srow) * DIM + chunk * 8;
    const _Float16* wb0 = Wz + (size_t)(n0 + srow) * DIM + chunk * 8;
    const _Float16* wb1 = Wz + (size_t)(n0 + 64 + srow) * DIM + chunk * 8;
    const int db0 = chunk * 2048 + srow * 16;          // LDS byte offsets
    const int db1 = chunk * 2048 + (64 + srow) * 16;

    floatx4 acc[4][4];
    #pragma unroll
    for (int m = 0; m < 4; m++)
        #pragma unroll
        for (int n = 0; n < 4; n++) acc[m][n] = floatx4{0.f, 0.f, 0.f, 0.f};

    floatx4 la0, la1, la2, la3;
    half8 lw0, lw1;

#define LOADS_K1(k0) do {                                                       \
    la0 = *(const floatx4*)(xa0 + (k0));                                        \
    la1 = *(const floatx4*)(xa0 + (k0) + 4);                                    \
    la2 = *(const floatx4*)(xa1 + (k0));                                        \
    la3 = *(const floatx4*)(xa1 + (k0) + 4);                                    \
    lw0 = *(const half8*)(wb0 + (k0));                                          \
    lw1 = *(const half8*)(wb1 + (k0));                                          \
} while (0)

#define WRITES_K1(bb) do {                                                      \
    half8 h0, h1;                                                               \
    _Pragma("unroll")                                                           \
    for (int j = 0; j < 4; j++) {                                               \
        h0[j] = (_Float16)la0[j]; h0[j + 4] = (_Float16)la1[j];                 \
        h1[j] = (_Float16)la2[j]; h1[j + 4] = (_Float16)la3[j];                 \
    }                                                                           \
    *(half8*)((char*)&AB[bb][0][0] + db0) = h0;                                 \
    *(half8*)((char*)&AB[bb][0][0] + db1) = h1;                                 \
    *(half8*)((char*)&AB[bb][1][0] + db0) = lw0;                                \
    *(half8*)((char*)&AB[bb][1][0] + db1) = lw1;                                \
} while (0)

    LOADS_K1(0);
    WRITES_K1(0);
    __syncthreads();

    for (int ks = 0; ks < 16; ks++) {
        const int cur = ks & 1;
        if (ks < 15) LOADS_K1((ks + 1) * 32);          // issue early (hide HBM)
        const _Float16* Ar = &AB[cur][0][lg * 1024 + (wr * 64 + l16) * 8];
        const _Float16* Br = &AB[cur][1][lg * 1024 + (wc * 64 + l16) * 8];
        half8 af[4], bf[4];
        #pragma unroll
        for (int m = 0; m < 4; m++) af[m] = *(const half8*)(Ar + m * 128);
        #pragma unroll
        for (int n = 0; n < 4; n++) bf[n] = *(const half8*)(Br + n * 128);
        #pragma unroll
        for (int m = 0; m < 4; m++)
            #pragma unroll
            for (int n = 0; n < 4; n++)
                acc[m][n] = __builtin_amdgcn_mfma_f32_16x16x32_f16(af[m], bf[n], acc[m][n], 0, 0, 0);
        if (ks < 15) {
            WRITES_K1(cur ^ 1);                        // cvt + write late
            __syncthreads();
        }
    }
#undef LOADS_K1
#undef WRITES_K1

    const float* bias = (z == 0) ? bq : ((z == 1) ? bk : bv);
    const float bscale = (z == 0) ? SCALE : 1.0f;
    #pragma unroll
    for (int n = 0; n < 4; n++) {
        const int ncol = n0 + wc * 64 + n * 16 + l16;
        const float bn = bias[ncol] * bscale;
        #pragma unroll
        for (int m = 0; m < 4; m++) {
            const int r0 = m0 + wr * 64 + m * 16 + lg * 4;  // quad never splits batch
            const int bb = r0 / NSEQ;
            const int i0 = r0 - bb * NSEQ;
            if (z < 2) {
                _Float16* O = (z == 0) ? qh : kh;
                #pragma unroll
                for (int j = 0; j < 4; j++)
                    O[((size_t)(bb * NPAD + i0 + j)) * DIM + ncol] = (_Float16)(acc[m][n][j] + bn);
            } else {
                half4 pk;
                #pragma unroll
                for (int j = 0; j < 4; j++) pk[j] = (_Float16)(acc[m][n][j] + bn);
                *(half4*)(vT + ((size_t)(bb * DIM + ncol)) * NPAD + i0) = pk;
            }
        }
    }
}

// ---------------------------------------------------------------------------
// K2: S = Q_scaled . K^T (64x384 per block), mask, softmax -> P (f16 global).
// grid (2,32,8), block 256 (4 waves; wave = 16 q x 384 keys, acc[24]).
// COALESCED K staging: lane -> (key-row = tid>>2 [+s*64], chunk = tid&3);
// reg-stage: 6 half8 loads early -> 6 ds_write_b128 late. LDS layout
// [k8][key][8] and all fragment reads unchanged. P: [b*32+w][128][384].
// ---------------------------------------------------------------------------
__global__ __launch_bounds__(256) void attn_scores(
    const _Float16* __restrict__ qh, const _Float16* __restrict__ kh,
    const int* __restrict__ mask, _Float16* __restrict__ P)
{
    const int h = blockIdx.x, w = blockIdx.y, b = blockIdx.z;
    const int tid = threadIdx.x;
    const int wid = tid >> 6, lane = tid & 63;
    const int l16 = lane & 15, lg = lane >> 4;

    __shared__ __align__(16) _Float16 Kl[2][12288];   // [k8*3072 + key*8], 24 KB/buf

    const int kbase = w * 128 - 128;
    const _Float16* khb = kh + (size_t)b * NPAD * DIM;

    const int srow  = tid >> 2;    // 0..63
    const int chunk = tid & 3;
    int rowoff[6], dbyte[6];
    #pragma unroll
    for (int c = 0; c < 6; c++) {
        int krow = c * 64 + srow;                     // 0..383
        int gk = kbase + krow;
        int gc = gk < 0 ? 0 : (gk > NPAD - 1 ? NPAD - 1 : gk);
        rowoff[c] = gc * DIM + chunk * 8;
        dbyte[c]  = chunk * 6144 + krow * 16;
    }

    const int qr0 = w * 128 + h * 64 + wid * 16;       // <= 4080
    const _Float16* qrow = qh + ((size_t)(b * NPAD + qr0 + l16)) * DIM + lg * 8;

    floatx4 acc[24];
    #pragma unroll
    for (int t = 0; t < 24; t++) acc[t] = floatx4{0.f, 0.f, 0.f, 0.f};

    half8 kld[6];
    // prologue: stage tile 0
    #pragma unroll
    for (int c = 0; c < 6; c++) kld[c] = *(const half8*)(khb + rowoff[c]);
    #pragma unroll
    for (int c = 0; c < 6; c++) *(half8*)((char*)&Kl[0][0] + dbyte[c]) = kld[c];
    half8 qcur = *(const half8*)(qrow);
    __syncthreads();

    for (int ks = 0; ks < 16; ks++) {
        const int cur = ks & 1;
        half8 qnext;
        if (ks < 15) {
            const int k0 = (ks + 1) * 32;
            #pragma unroll
            for (int c = 0; c < 6; c++) kld[c] = *(const half8*)(khb + rowoff[c] + k0);
            qnext = *(const half8*)(qrow + k0);
        }
        const _Float16* Kb = &Kl[cur][lg * 3072 + l16 * 8];
        #pragma unroll
        for (int t = 0; t < 24; t++) {
            half8 bf = *(const half8*)(Kb + t * 128);
            acc[t] = __builtin_amdgcn_mfma_f32_16x16x32_f16(qcur, bf, acc[t], 0, 0, 0);
        }
        if (ks < 15) {
            #pragma unroll
            for (int c = 0; c < 6; c++) *(half8*)((char*)&Kl[cur ^ 1][0] + dbyte[c]) = kld[c];
            __syncthreads();
            qcur = qnext;
        }
    }

    // mask: keep iff key in [0,4000) and mask[b][g] != 0
    const int* mb = mask + b * NSEQ;
    #pragma unroll
    for (int t = 0; t < 24; t++) {
        int gk = kbase + t * 16 + l16;
        bool keep = (gk >= 0) && (gk < NSEQ) && (mb[(gk >= 0 && gk < NSEQ) ? gk : 0] != 0);
        if (!keep) acc[t] = floatx4{NEG_MAX, NEG_MAX, NEG_MAX, NEG_MAX};
    }

    _Float16* Pw = P + ((size_t)(b * NWIN + w)) * 128 * 384
                     + (size_t)(h * 64 + wid * 16) * 384;
    #pragma unroll
    for (int j = 0; j < 4; j++) {
        float mj = NEG_MAX;
        #pragma unroll
        for (int t = 0; t < 24; t++) mj = fmaxf(mj, acc[t][j]);
        mj = fmaxf(mj, __shfl_xor(mj, 1));
        mj = fmaxf(mj, __shfl_xor(mj, 2));
        mj = fmaxf(mj, __shfl_xor(mj, 4));
        mj = fmaxf(mj, __shfl_xor(mj, 8));

        float p[24];
        float lsum = 0.f;
        #pragma unroll
        for (int t = 0; t < 24; t++) { p[t] = __expf(acc[t][j] - mj); lsum += p[t]; }
        lsum += __shfl_xor(lsum, 1);
        lsum += __shfl_xor(lsum, 2);
        lsum += __shfl_xor(lsum, 4);
        lsum += __shfl_xor(lsum, 8);
        float rinv = 1.0f / lsum;

        int r = lg * 4 + j;
        #pragma unroll
        for (int t = 0; t < 24; t++)
            Pw[(size_t)r * 384 + t * 16 + l16] = (_Float16)(p[t] * rinv);
    }
}

// ---------------------------------------------------------------------------
// K3: O = P . V (128 q x 128 d per block). grid (4,32,8), block 256 (4 waves;
// wave = 32q x 128d, acc[2][8]). COALESCED P/V staging: lane -> (row = tid>>2
// [+0/64], chunk = tid&3); reg-stage 4 half8 loads early -> 4 ds_write_b128
// late. LDS layouts and fragment reads unchanged. Clamped V-columns always
// multiply P == 0 (masked keys).
// ---------------------------------------------------------------------------
__global__ __launch_bounds__(256) void attn_pv(
    const _Float16* __restrict__ P, const _Float16* __restrict__ vT,
    float* __restrict__ out)
{
    const int dq = blockIdx.x, w = blockIdx.y, b = blockIdx.z;
    const int tid = threadIdx.x;
    const int wid = tid >> 6, lane = tid & 63;
    const int l16 = lane & 15, lg = lane >> 4;
    const int d0 = dq * 128;

    __shared__ __align__(16) _Float16 Pl[2][4096];   // [i8*1024 + q*8]
    __shared__ __align__(16) _Float16 Vl[2][4096];   // [i8*1024 + d*8]

    const _Float16* Pw = P + ((size_t)(b * NWIN + w)) * 128 * 384;
    const _Float16* vb = vT + (size_t)b * DIM * NPAD;
    const int iw_base = w * 128 - 128;

    const int srow  = tid >> 2;    // 0..63
    const int chunk = tid & 3;
    const int db0 = chunk * 2048 + srow * 16;
    const int db1 = chunk * 2048 + (64 + srow) * 16;
    const _Float16* pp0 = Pw + (size_t)srow * 384 + chunk * 8;
    const _Float16* pp1 = Pw + (size_t)(64 + srow) * 384 + chunk * 8;
    const _Float16* vv0 = vb + (size_t)(d0 + srow) * NPAD;
    const _Float16* vv1 = vb + (size_t)(d0 + 64 + srow) * NPAD;

    half8 pl0, pl1, vl0, vl1;

#define LOADS_K3(ks) do {                                                       \
    const int i0 = (ks) * 32;                                                   \
    pl0 = *(const half8*)(pp0 + i0);                                            \
    pl1 = *(const half8*)(pp1 + i0);                                            \
    int ig = iw_base + i0 + chunk * 8;                                          \
    ig = ig < 0 ? 0 : (ig > NPAD - 8 ? NPAD - 8 : ig);                          \
    vl0 = *(const half8*)(vv0 + ig);                                            \
    vl1 = *(const half8*)(vv1 + ig);                                            \
} while (0)

#define WRITES_K3(bb) do {                                                      \
    *(half8*)((char*)&Pl[bb][0] + db0) = pl0;                                   \
    *(half8*)((char*)&Pl[bb][0] + db1) = pl1;                                   \
    *(half8*)((char*)&Vl[bb][0] + db0) = vl0;                                   \
    *(half8*)((char*)&Vl[bb][0] + db1) = vl1;                                   \
} while (0)

    floatx4 acc[2][8];
    #pragma unroll
    for (int m = 0; m < 2; m++)
        #pragma unroll
        for (int n = 0; n < 8; n++) acc[m][n] = floatx4{0.f, 0.f, 0.f, 0.f};

    LOADS_K3(0);
    WRITES_K3(0);
    __syncthreads();
    for (int ks = 0; ks < 12; ks++) {
        const int cur = ks & 1;
        if (ks < 11) LOADS_K3(ks + 1);
        const _Float16* Pr = &Pl[cur][lg * 1024 + (wid * 32 + l16) * 8];
        const _Float16* Vr = &Vl[cur][lg * 1024 + l16 * 8];
        half8 pa[2], vf[8];
        #pragma unroll
        for (int m = 0; m < 2; m++) pa[m] = *(const half8*)(Pr + m * 128);
        #pragma unroll
        for (int n = 0; n < 8; n++) vf[n] = *(const half8*)(Vr + n * 128);
        #pragma unroll
        for (int m = 0; m < 2; m++)
            #pragma unroll
            for (int n = 0; n < 8; n++)
                acc[m][n] = __builtin_amdgcn_mfma_f32_16x16x32_f16(pa[m], vf[n], acc[m][n], 0, 0, 0);
        if (ks < 11) {
            WRITES_K3(cur ^ 1);
            __syncthreads();
        }
    }
#undef LOADS_K3
#undef WRITES_K3

    #pragma unroll
    for (int m = 0; m < 2; m++) {
        #pragma unroll
        for (int j = 0; j < 4; j++) {
            int i = w * 128 + wid * 32 + m * 16 + lg * 4 + j;
            if (i < NSEQ) {
                float* orow = out + ((size_t)b * NSEQ + i) * DIM + d0;
                #pragma unroll
                for (int n = 0; n < 8; n++) orow[n * 16 + l16] = acc[m][n][j];
            }
        }
    }
}

// ---------------------------------------------------------------------------
extern "C" void kernel_launch(void* const* d_in, const int* in_sizes, int n_in,
                              void* d_out, int out_size, void* d_ws, size_t ws_size,
                              hipStream_t stream)
{
    const float* xq = (const float*)d_in[0];
    const float* xk = (const float*)d_in[1];
    const float* xv = (const float*)d_in[2];
    const int*  msk = (const int*)d_in[3];
    const float* wq = (const float*)d_in[4];
    const float* bq = (const float*)d_in[5];
    const float* wk = (const float*)d_in[6];
    const float* bk = (const float*)d_in[7];
    const float* wv = (const float*)d_in[8];
    const float* bv = (const float*)d_in[9];

    // ws (f16 elems): qh/kh/vT 16,777,216 each | wh 786,432 | P 12,582,912
    _Float16* qh = (_Float16*)d_ws;                       // [8][4096][512]
    _Float16* kh = qh + (size_t)NB * NPAD * DIM;          // [8][4096][512]
    _Float16* vT = kh + (size_t)NB * NPAD * DIM;          // [8][512][4096]
    _Float16* wh = vT + (size_t)NB * NPAD * DIM;          // [3][512][512]
    _Float16* P  = wh + (size_t)3 * DIM * DIM;            // [256][128][384]
    float* out = (float*)d_out;

    convert_w<<<dim3(256), dim3(256), 0, stream>>>(wq, wk, wv, wh);
    proj_gemm<<<dim3(3008), dim3(256), 0, stream>>>(
        xq, xk, xv, wh, bq, bk, bv, qh, kh, vT);
    attn_scores<<<dim3(2, NWIN, NB), dim3(256), 0, stream>>>(qh, kh, msk, P);
    attn_pv<<<dim3(4, NWIN, NB), dim3(256), 0, stream>>>(P, vT, out);
}